// Round 4
// baseline (105.502 us; speedup 1.0000x reference)
//
#include <hip/hip_runtime.h>
#include <hip/hip_bf16.h>

// HybridSurvivalQ: quantum expval collapses to prod_{q=1..6} cos(x_q[q]+p[q])
// (CNOT ring permutes basis states; final bit0 = parity of bits 1..6;
//  E[(-1)^{b_q}] = cos^2-sin^2 = cos(x+p) per qubit; qubit 0 marginalizes out).
// Then MLP 65->32->16->1 with ReLU. One thread per row, fp32 vector ALU.
//
// R1: dur_us is harness-dominated (two 42.5us poison fills of 268MB d_ws +
//     input restore ~= 91us floor); kernel tail is the controllable ~11us.
// R2: runtime-indexed per-thread arrays -> scratch -> post-timing divergence
//     under graph replay. All register arrays must use constant indices.
// R3: rolled load->waitcnt(0)->FMA chain exposes memory latency to only
//     2 waves/SIMD (grid is exactly 2048 waves; occupancy is capped by the
//     grid, so VGPRs are free). Fix: distance-2 rotating prefetch of x_c so
//     vmcnt waits overlap the 128-FMA blocks. Weights stay wave-uniform
//     (s_load batches) in a rolled loop; layer 2/3 fully unrolled.

#define NQ 7
#define F  64
#define H1 32
#define H2 16

// 128 FMAs: acc1 += outer(xv, W1 rows 4k+1..4k+4), weights wave-uniform.
#define L1_BLOCK(xv, w)                                                        \
    do {                                                                       \
        _Pragma("unroll")                                                      \
        for (int j = 0; j < H1; ++j) acc1[j] = fmaf((xv).x, (w)[j],          acc1[j]); \
        _Pragma("unroll")                                                      \
        for (int j = 0; j < H1; ++j) acc1[j] = fmaf((xv).y, (w)[H1 + j],     acc1[j]); \
        _Pragma("unroll")                                                      \
        for (int j = 0; j < H1; ++j) acc1[j] = fmaf((xv).z, (w)[2 * H1 + j], acc1[j]); \
        _Pragma("unroll")                                                      \
        for (int j = 0; j < H1; ++j) acc1[j] = fmaf((xv).w, (w)[3 * H1 + j], acc1[j]); \
    } while (0)

__global__ __launch_bounds__(256) void hybrid_fused(
    const float* __restrict__ x_q, const float* __restrict__ x_c,
    const float* __restrict__ q_params,
    const float* __restrict__ W1, const float* __restrict__ b1,
    const float* __restrict__ W2, const float* __restrict__ b2,
    const float* __restrict__ W3, const float* __restrict__ b3,
    float* __restrict__ out, int B)
{
    const int row = blockIdx.x * 256 + threadIdx.x;
    if (row >= B) return;

    const float4* xc4 = reinterpret_cast<const float4*>(x_c + (size_t)row * F);

    // Prime the pipeline: 2 x_c loads in flight before any dependent use.
    float4 c0 = xc4[0];
    float4 c1 = xc4[1];

    // ---- quantum expectation (closed form); overlaps with loads above ----
    float qv = 1.0f;
    #pragma unroll
    for (int q = 1; q < NQ; ++q) {
        qv *= __cosf(x_q[(size_t)row * NQ + q] + q_params[q]);
    }

    // ---- layer 1: combined(65) @ W1(65x32) + b1 ----
    float acc1[H1];
    #pragma unroll
    for (int j = 0; j < H1; ++j)
        acc1[j] = fmaf(qv, W1[j], b1[j]);   // k = 0 row (constant idx)

    const float* w = W1 + H1;               // rows 1..64, advanced 4 rows/iter
    #pragma unroll 1   // rolled: distance-2 prefetch keeps 2 loads in flight
    for (int k4 = 0; k4 < F / 4 - 2; ++k4) {
        const float4 c2 = xc4[k4 + 2];      // prefetch
        L1_BLOCK(c0, w);
        c0 = c1;
        c1 = c2;
        w += 4 * H1;
    }
    // Drain the pipeline (k4 = 14, 15).
    L1_BLOCK(c0, w);  w += 4 * H1;
    L1_BLOCK(c1, w);

    // ---- layer 2: relu(acc1)(32) @ W2(32x16) + b2 (fully unrolled) ----
    float acc2[H2];
    #pragma unroll
    for (int j = 0; j < H2; ++j) acc2[j] = b2[j];
    #pragma unroll
    for (int k = 0; k < H1; ++k) {
        const float h = fmaxf(acc1[k], 0.0f);
        #pragma unroll
        for (int j = 0; j < H2; ++j)
            acc2[j] = fmaf(h, W2[k * H2 + j], acc2[j]);
    }

    // ---- layer 3: relu(acc2)(16) @ W3(16x1) + b3 ----
    float o = b3[0];
    #pragma unroll
    for (int k = 0; k < H2; ++k)
        o = fmaf(fmaxf(acc2[k], 0.0f), W3[k], o);

    out[row] = o;
}

extern "C" void kernel_launch(void* const* d_in, const int* in_sizes, int n_in,
                              void* d_out, int out_size, void* d_ws, size_t ws_size,
                              hipStream_t stream) {
    const float* x_q      = (const float*)d_in[0];
    const float* x_c      = (const float*)d_in[1];
    const float* q_params = (const float*)d_in[2];
    const float* W1       = (const float*)d_in[3];
    const float* b1       = (const float*)d_in[4];
    const float* W2       = (const float*)d_in[5];
    const float* b2       = (const float*)d_in[6];
    const float* W3       = (const float*)d_in[7];
    const float* b3       = (const float*)d_in[8];
    float* out = (float*)d_out;

    const int B = in_sizes[0] / NQ;   // 131072
    const int grid = (B + 255) / 256; // 512 blocks of 256

    hybrid_fused<<<grid, 256, 0, stream>>>(x_q, x_c, q_params,
                                           W1, b1, W2, b2, W3, b3,
                                           out, B);
}

// Round 5
// 102.848 us; speedup vs baseline: 1.0258x; 1.0258x over previous
//
#include <hip/hip_runtime.h>
#include <hip/hip_bf16.h>

// HybridSurvivalQ: quantum expval collapses to prod_{q=1..6} cos(x_q[q]+p[q])
// (CNOT ring permutes basis states; final bit0 = parity of bits 1..6;
//  E[(-1)^{b_q}] = cos^2-sin^2 = cos(x+p) per qubit; qubit 0 marginalizes out).
// Then MLP 65->32->16->1 with ReLU. One thread per row, fp32 vector ALU.
//
// R1: dur_us is harness-dominated: ~92us of per-replay reset traffic
//     (2x 268MB d_ws poison fills at 42-46us + ~38MB input restore). The
//     kernel contributes only ~10-13us; fills vary +-8% run-to-run, so
//     kernel deltas under ~4us are below the measurement noise floor.
// R2: runtime-indexed per-thread arrays -> scratch -> post-timing divergence
//     under graph replay. All register arrays must use constant indices.
// R4: explicit distance-2 prefetch was neutral (102.2 -> 105.5, within
//     noise); compiler scheduling of the rolled loop + 2 waves/SIMD TLP +
//     L1-resident weights already cover the latency. Reverted to R3 form.
// Kernel floor: max(38.3MB/6.3TB/s ~= 6.1us mem, 2640 VALU inst ~= 4.4us)
//     ~= 6us; inferred actual ~10-13us; remaining headroom < noise.

#define NQ 7
#define F  64
#define H1 32
#define H2 16

__global__ __launch_bounds__(256) void hybrid_fused(
    const float* __restrict__ x_q, const float* __restrict__ x_c,
    const float* __restrict__ q_params,
    const float* __restrict__ W1, const float* __restrict__ b1,
    const float* __restrict__ W2, const float* __restrict__ b2,
    const float* __restrict__ W3, const float* __restrict__ b3,
    float* __restrict__ out, int B)
{
    const int row = blockIdx.x * 256 + threadIdx.x;
    if (row >= B) return;

    // ---- quantum expectation (closed form) ----
    float qv = 1.0f;
    #pragma unroll
    for (int q = 1; q < NQ; ++q) {
        qv *= __cosf(x_q[(size_t)row * NQ + q] + q_params[q]);
    }

    // ---- layer 1: combined(65) @ W1(65x32) + b1 ----
    // combined[0] = qv, combined[1+f] = x_c[f]
    float acc1[H1];
    #pragma unroll
    for (int j = 0; j < H1; ++j)
        acc1[j] = fmaf(qv, W1[j], b1[j]);   // k = 0 row of W1 (constant idx)

    const float4* xc4 = reinterpret_cast<const float4*>(x_c + (size_t)row * F);
    #pragma unroll 1   // rolled: 16 iters; body = uniform weight loads + 128 FMA
    for (int k4 = 0; k4 < F / 4; ++k4) {
        const float4 xv = xc4[k4];
        const float* w = W1 + (size_t)(1 + 4 * k4) * H1;  // wave-uniform -> s_load
        #pragma unroll
        for (int j = 0; j < H1; ++j) acc1[j] = fmaf(xv.x, w[j],          acc1[j]);
        #pragma unroll
        for (int j = 0; j < H1; ++j) acc1[j] = fmaf(xv.y, w[H1 + j],     acc1[j]);
        #pragma unroll
        for (int j = 0; j < H1; ++j) acc1[j] = fmaf(xv.z, w[2 * H1 + j], acc1[j]);
        #pragma unroll
        for (int j = 0; j < H1; ++j) acc1[j] = fmaf(xv.w, w[3 * H1 + j], acc1[j]);
    }

    // ---- layer 2: relu(acc1)(32) @ W2(32x16) + b2 ----
    // FULLY unrolled: all acc1/acc2 indices constant -> registers, no scratch.
    float acc2[H2];
    #pragma unroll
    for (int j = 0; j < H2; ++j) acc2[j] = b2[j];
    #pragma unroll
    for (int k = 0; k < H1; ++k) {
        const float h = fmaxf(acc1[k], 0.0f);
        #pragma unroll
        for (int j = 0; j < H2; ++j)
            acc2[j] = fmaf(h, W2[k * H2 + j], acc2[j]);
    }

    // ---- layer 3: relu(acc2)(16) @ W3(16x1) + b3 ----
    float o = b3[0];
    #pragma unroll
    for (int k = 0; k < H2; ++k)
        o = fmaf(fmaxf(acc2[k], 0.0f), W3[k], o);

    out[row] = o;
}

extern "C" void kernel_launch(void* const* d_in, const int* in_sizes, int n_in,
                              void* d_out, int out_size, void* d_ws, size_t ws_size,
                              hipStream_t stream) {
    const float* x_q      = (const float*)d_in[0];
    const float* x_c      = (const float*)d_in[1];
    const float* q_params = (const float*)d_in[2];
    const float* W1       = (const float*)d_in[3];
    const float* b1       = (const float*)d_in[4];
    const float* W2       = (const float*)d_in[5];
    const float* b2       = (const float*)d_in[6];
    const float* W3       = (const float*)d_in[7];
    const float* b3       = (const float*)d_in[8];
    float* out = (float*)d_out;

    const int B = in_sizes[0] / NQ;   // 131072
    const int grid = (B + 255) / 256; // 512 blocks of 256

    hybrid_fused<<<grid, 256, 0, stream>>>(x_q, x_c, q_params,
                                           W1, b1, W2, b2, W3, b3,
                                           out, B);
}